// Round 24
// baseline (60.213 us; speedup 1.0000x reference)
//
#include <hip/hip_runtime.h>
#include <hip/hip_bf16.h>

#define BB 4
#define NN 4096
#define DIN 512
#define DD 64

typedef __attribute__((ext_vector_type(8))) short short8;
typedef __attribute__((ext_vector_type(4))) float f32x4;
typedef __attribute__((ext_vector_type(4))) unsigned short us4;
typedef __attribute__((ext_vector_type(2))) unsigned int u32x2;
using bf16 = __hip_bfloat16;

// 0.125 * log2(e): QK^T scores come out in base-2 log-units
#define QSCALE 0.18033688011112042f

__device__ inline void mfma_16x16x32(f32x4& d, short8 a, short8 b) {
    asm("v_mfma_f32_16x16x32_bf16 %0, %1, %2, %0" : "+v"(d) : "v"(a), "v"(b));
}

__device__ inline unsigned cvt_pk_bf16(float lo, float hi) {
    unsigned r;
    asm("v_cvt_pk_bf16_f32 %0, %1, %2" : "=v"(r) : "v"(lo), "v"(hi));
    return r;
}

__device__ inline short8 load_cvt8(const float* __restrict__ src) {
    f32x4 f0 = *(const f32x4*)(src);
    f32x4 f1 = *(const f32x4*)(src + 4);
    bf16 t[8];
    #pragma unroll
    for (int j = 0; j < 4; ++j) t[j]     = __float2bfloat16(f0[j]);
    #pragma unroll
    for (int j = 0; j < 4; ++j) t[4 + j] = __float2bfloat16(f1[j]);
    return *(short8*)t;
}

// 64-key tiles: T(qt) = qt+1; unit = 2^cl tiles
// pfx(qt) = sum_{j<qt} ceil((j+1)/2^cl)
__host__ __device__ inline int pfx(int qt, int cl) {
    int C = 1 << cl;
    int a = qt >> cl;
    int r = qt & (C - 1);
    return C * a * (a + 1) / 2 + r * (a + 1);
}

// ---------------- W transpose+convert: WT[g][kk] = W_{g/64}[kk][g%64] -----
__global__ __launch_bounds__(256) void convw_kernel(
    const float* __restrict__ Wq, const float* __restrict__ Wk,
    const float* __restrict__ Wv, bf16* __restrict__ WT)
{
    int idx = blockIdx.x * 256 + threadIdx.x;   // 3*64*512 = 98304
    int w   = idx >> 15;
    int rem = idx & 32767;
    int n   = rem >> 9;
    int kk  = rem & 511;
    const float* W = (w == 0) ? Wq : (w == 1) ? Wk : Wv;
    WT[idx] = __float2bfloat16(W[kk * DD + n]);
}

// ---------------- MFMA projection: 64 rows/block, LDS-staged x ------------
__global__ __launch_bounds__(256) void proj_kernel(
    const float* __restrict__ x, const bf16* __restrict__ WT,
    bf16* __restrict__ q, bf16* __restrict__ k, bf16* __restrict__ vT)
{
    __shared__ __align__(16) char xs[65536];   // 64 rows x 512 bf16, swizzled
    const int tid   = threadIdx.x;
    const int row0  = blockIdx.x * 64;
    const int b     = row0 >> 12;
    const int nrow0 = row0 & 4095;

    const float* xb = x + (size_t)row0 * DIN;
    #pragma unroll
    for (int i = 0; i < 16; ++i) {
        int c   = tid + i * 256;               // 0..4095
        int row = c >> 6;
        int cc  = c & 63;
        const float* src = xb + row * DIN + cc * 8;
        int off = row * 1024 + ((cc * 16) ^ ((row & 7) << 4));
        *(short8*)(xs + off) = load_cvt8(src);
    }
    __syncthreads();

    const int lane  = tid & 63;
    const int l16   = lane & 15;
    const int lg    = lane >> 4;
    const int wave  = tid >> 6;
    const int cbase = wave * 48;

    f32x4 acc[4][3];
    #pragma unroll
    for (int rt = 0; rt < 4; ++rt)
        #pragma unroll
        for (int ct = 0; ct < 3; ++ct) acc[rt][ct] = (f32x4){0.f, 0.f, 0.f, 0.f};

    const bf16* wb = WT + (size_t)(cbase + l16) * DIN + lg * 8;

    #pragma unroll 2
    for (int ks = 0; ks < 16; ++ks) {
        short8 a[4], bfr[3];
        #pragma unroll
        for (int rt = 0; rt < 4; ++rt) {
            int row = rt * 16 + l16;
            a[rt] = *(const short8*)(xs + row * 1024 +
                                     ((ks * 64 + lg * 16) ^ ((row & 7) << 4)));
        }
        #pragma unroll
        for (int ct = 0; ct < 3; ++ct)
            bfr[ct] = *(const short8*)(wb + ct * 16 * DIN + ks * 32);
        #pragma unroll
        for (int rt = 0; rt < 4; ++rt)
            #pragma unroll
            for (int ct = 0; ct < 3; ++ct)
                mfma_16x16x32(acc[rt][ct], a[rt], bfr[ct]);
    }

    #pragma unroll
    for (int ct = 0; ct < 3; ++ct) {
        int g = cbase + ct * 16 + l16;
        int w = g >> 6;
        int n = g & 63;
        #pragma unroll
        for (int rt = 0; rt < 4; ++rt) {
            if (w == 2) {
                us4 pv;
                #pragma unroll
                for (int r = 0; r < 4; ++r) {
                    bf16 hv = __float2bfloat16(acc[rt][ct][r]);
                    pv[r] = *(unsigned short*)&hv;
                }
                *(us4*)(vT + ((size_t)b * DD + n) * NN + nrow0 + rt * 16 + lg * 4) = pv;
            } else {
                bf16* dst = (w == 0) ? q : k;
                float sc  = (w == 0) ? QSCALE : 1.0f;
                #pragma unroll
                for (int r = 0; r < 4; ++r) {
                    int row = nrow0 + rt * 16 + lg * 4 + r;
                    dst[((size_t)b * NN + row) * DD + n] =
                        __float2bfloat16(acc[rt][ct][r] * sc);
                }
            }
        }
    }
}

// ---------------- equal-work split-KV flash attention, 64-key tiles -------
// double-buffered K/V staging: ONE barrier per tile. 40KB LDS / block.
// swapped-QK layout: lane holds P[qrow = l16][keys ct*16 + lg*4 + r]
// U==1 units (qt <= 7) write normalized output directly
__global__ __launch_bounds__(256) void attn_split_kernel(
    const bf16* __restrict__ q, const bf16* __restrict__ k,
    const bf16* __restrict__ vT,
    unsigned short* __restrict__ partO, float* __restrict__ partML,
    float* __restrict__ out, int cl)
{
    const int perB = pfx(64, cl);
    const int wblk = blockIdx.x;
    const int b    = wblk / perB;
    const int u    = wblk - b * perB;
    int lo = 0, hi = 63;
    while (lo < hi) {
        int mid = (lo + hi + 1) >> 1;
        if (pfx(mid, cl) <= u) lo = mid; else hi = mid - 1;
    }
    const int qt = lo;
    const int s  = u - pfx(qt, cl);
    const size_t sidx = (size_t)wblk;        // canonical partial slot

    const int C  = 1 << cl;
    const int T  = qt + 1;                   // # 64-key tiles for this qt
    const int t0 = s << cl;
    int t1 = t0 + C; if (t1 > T) t1 = T;
    const int U  = (qt + C) >> cl;           // # units for this qt

    const int wave = threadIdx.x >> 6;
    const int lane = threadIdx.x & 63;
    const int l16  = lane & 15;
    const int lg   = lane >> 4;

    __shared__ __align__(16) char klds[2][8192];    // 64 keys x 128B, dbuf
    __shared__ __align__(16) char vlds[2][8192];    // 64 dd x 128B, dbuf
    __shared__ __align__(16) char plds[4][2048];    // per-wave P buffer
    char* pbl = plds[wave];
    const int swz = (l16 & 7) << 4;

    const int row0g = qt * 64 + wave * 16;
    const int qrow  = row0g + l16;           // this lane's softmax row

    const bf16* qbase = q + ((size_t)b * NN + row0g + l16) * DD + lg * 8;
    short8 qfrag0 = *(const short8*)(qbase);
    short8 qfrag1 = *(const short8*)(qbase + 32);

    f32x4 oacc[4];
    #pragma unroll
    for (int dt = 0; dt < 4; ++dt) oacc[dt] = (f32x4){0.f, 0.f, 0.f, 0.f};
    float m = -INFINITY, l = 0.f;

    // ---- staging geometry: 256 threads x 2 x 16B for each of K and V ----
    const char* kglob = (const char*)(k  + (size_t)b * NN * DD);  // +t*8192
    const char* vglob = (const char*)(vT + (size_t)b * DD * NN);  // +dd*8192 +t*128
    short8 kst[2], vst[2];
    int k_src[2], k_wr[2], v_src[2], v_wr[2];
    #pragma unroll
    for (int i = 0; i < 2; ++i) {
        int L = threadIdx.x * 16 + i * 4096;             // 0..8191
        k_src[i] = L;
        k_wr[i]  = L ^ (((L >> 7) & 7) << 4);
        int dd    = L >> 7;
        int inner = L & 127;
        v_src[i] = dd * 8192 + inner;                    // + t*128 at use
        v_wr[i]  = dd * 128 + (inner ^ ((dd & 7) << 4));
    }

    // prologue: load + write tile t0 into buffer 0
    {
        const char* kt = kglob + (size_t)t0 * 8192;
        const char* vt = vglob + (size_t)t0 * 128;
        #pragma unroll
        for (int i = 0; i < 2; ++i) kst[i] = *(const short8*)(kt + k_src[i]);
        #pragma unroll
        for (int i = 0; i < 2; ++i) vst[i] = *(const short8*)(vt + v_src[i]);
        #pragma unroll
        for (int i = 0; i < 2; ++i) *(short8*)(klds[0] + k_wr[i]) = kst[i];
        #pragma unroll
        for (int i = 0; i < 2; ++i) *(short8*)(vlds[0] + v_wr[i]) = vst[i];
    }
    __syncthreads();

    int cur = 0;
    #pragma unroll 1
    for (int t = t0; t < t1; ++t) {
        const char* kb = klds[cur];
        const char* vb = vlds[cur];

        // ---- S = K Q^T from LDS (swapped operands), 64 keys ----
        f32x4 sc[4];
        #pragma unroll
        for (int ct = 0; ct < 4; ++ct) sc[ct] = (f32x4){0.f, 0.f, 0.f, 0.f};
        __builtin_amdgcn_s_setprio(1);
        #pragma unroll
        for (int ct = 0; ct < 4; ++ct) {
            short8 kf0 = *(const short8*)(kb + (ct * 16 + l16) * 128 + ((lg * 16) ^ swz));
            short8 kf1 = *(const short8*)(kb + (ct * 16 + l16) * 128 + ((64 + lg * 16) ^ swz));
            mfma_16x16x32(sc[ct], kf0, qfrag0);
            mfma_16x16x32(sc[ct], kf1, qfrag1);
        }
        __builtin_amdgcn_s_setprio(0);

        // ---- prefetch next tile into registers, write into other buffer ----
        if (t + 1 < t1) {
            const char* kt = kglob + (size_t)(t + 1) * 8192;
            const char* vt = vglob + (size_t)(t + 1) * 128;
            #pragma unroll
            for (int i = 0; i < 2; ++i) kst[i] = *(const short8*)(kt + k_src[i]);
            #pragma unroll
            for (int i = 0; i < 2; ++i) vst[i] = *(const short8*)(vt + v_src[i]);
            #pragma unroll
            for (int i = 0; i < 2; ++i) *(short8*)(klds[cur ^ 1] + k_wr[i]) = kst[i];
            #pragma unroll
            for (int i = 0; i < 2; ++i) *(short8*)(vlds[cur ^ 1] + v_wr[i]) = vst[i];
        }

        // ---- causal mask (only on diagonal-touching tiles) ----
        if (t * 64 + 63 > row0g) {
            #pragma unroll
            for (int ct = 0; ct < 4; ++ct) {
                int gk = t * 64 + ct * 16 + lg * 4;
                #pragma unroll
                for (int r = 0; r < 4; ++r)
                    if (gk + r > qrow)
                        sc[ct][r] = -INFINITY;
            }
        }

        // ---- in-register softmax, base-2 (one q-row per lane) ----
        float m4[4];
        #pragma unroll
        for (int ct = 0; ct < 4; ++ct)
            m4[ct] = fmaxf(fmaxf(sc[ct][0], sc[ct][1]), fmaxf(sc[ct][2], sc[ct][3]));
        float mt = fmaxf(fmaxf(m4[0], m4[1]), fmaxf(m4[2], m4[3]));
        mt = fmaxf(mt, __shfl_xor(mt, 16));
        mt = fmaxf(mt, __shfl_xor(mt, 32));

        float mn    = fmaxf(m, mt);
        float alpha = exp2f(m - mn);
        m = mn;

        float s4[4];
        #pragma unroll
        for (int ct = 0; ct < 4; ++ct) {
            float p0 = exp2f(sc[ct][0] - m);
            float p1 = exp2f(sc[ct][1] - m);
            float p2 = exp2f(sc[ct][2] - m);
            float p3 = exp2f(sc[ct][3] - m);
            sc[ct][0] = p0; sc[ct][1] = p1; sc[ct][2] = p2; sc[ct][3] = p3;
            s4[ct] = (p0 + p1) + (p2 + p3);
        }
        float ls = (s4[0] + s4[1]) + (s4[2] + s4[3]);
        ls += __shfl_xor(ls, 16);
        ls += __shfl_xor(ls, 32);
        l = l * alpha + ls;

        // alpha redistribution to D-layout rows (lg*4+r) + O rescale
        float ar[4];
        #pragma unroll
        for (int r = 0; r < 4; ++r) ar[r] = __shfl(alpha, lg * 4 + r);
        #pragma unroll
        for (int dt = 0; dt < 4; ++dt)
            #pragma unroll
            for (int r = 0; r < 4; ++r)
                oacc[dt][r] *= ar[r];

        // ---- P -> per-wave LDS (b64 writes, swizzled), read back A-frags ----
        #pragma unroll
        for (int ct = 0; ct < 4; ++ct) {
            u32x2 pw = (u32x2){cvt_pk_bf16(sc[ct][0], sc[ct][1]),
                               cvt_pk_bf16(sc[ct][2], sc[ct][3])};
            *(u32x2*)(pbl + l16 * 128 + ((ct * 32 + lg * 8) ^ swz)) = pw;
        }
        asm volatile("s_waitcnt lgkmcnt(0)" ::: "memory");
        short8 pa[2];
        #pragma unroll
        for (int kc = 0; kc < 2; ++kc)
            pa[kc] = *(const short8*)(pbl + l16 * 128 + ((kc * 64 + lg * 16) ^ swz));

        // ---- O += P V, V from LDS ----
        __builtin_amdgcn_s_setprio(1);
        #pragma unroll
        for (int dt = 0; dt < 4; ++dt) {
            short8 vf0 = *(const short8*)(vb + (dt * 16 + l16) * 128 + ((lg * 16) ^ swz));
            short8 vf1 = *(const short8*)(vb + (dt * 16 + l16) * 128 + ((64 + lg * 16) ^ swz));
            mfma_16x16x32(oacc[dt], pa[0], vf0);
            mfma_16x16x32(oacc[dt], pa[1], vf1);
        }
        __builtin_amdgcn_s_setprio(0);

        // ---- single barrier: publish t+1 writes, close t reads ----
        if (t + 1 < t1) {
            __syncthreads();
            cur ^= 1;
        }
    }

    if (U == 1) {
        // sole unit for this (b,qt): write normalized output directly
        float lr[4];
        #pragma unroll
        for (int r = 0; r < 4; ++r) lr[r] = __shfl(l, lg * 4 + r);
        #pragma unroll
        for (int dt = 0; dt < 4; ++dt) {
            #pragma unroll
            for (int r = 0; r < 4; ++r) {
                int row = row0g + lg * 4 + r;
                out[((size_t)b * NN + row) * DD + dt * 16 + l16] =
                    oacc[dt][r] / lr[r];
            }
        }
        return;
    }

    // ---- write partials: bf16, [sidx][wave][lane][16 regs] (contiguous) ----
    {
        unsigned short hv[16];
        #pragma unroll
        for (int dt = 0; dt < 4; ++dt)
            #pragma unroll
            for (int r = 0; r < 4; ++r) {
                bf16 h = __float2bfloat16(oacc[dt][r]);
                hv[dt * 4 + r] = *(unsigned short*)&h;
            }
        unsigned short* dst = partO + sidx * 4096 + wave * 1024 + lane * 16;
        *(short8*)(dst)     = *(short8*)(hv);
        *(short8*)(dst + 8) = *(short8*)(hv + 8);
    }
    if (lg == 0) {
        partML[sidx * 128 + wave * 16 + l16]      = m;
        partML[sidx * 128 + 64 + wave * 16 + l16] = l;
    }
}

// ---------------- combine partials: 512 blocks, 8 regs each ---------------
__global__ __launch_bounds__(256) void combine_kernel(
    const unsigned short* __restrict__ partO, const float* __restrict__ partML,
    float* __restrict__ out, int cl)
{
    const int blk2 = blockIdx.x;             // (b*64+qt)*2 + half
    const int half = blk2 & 1;
    const int blk  = blk2 >> 1;
    const int qt   = blk & 63;
    const int b    = blk >> 6;

    const int C = 1 << cl;
    const int U = (qt + C) >> cl;            // # work units for this qt
    if (U == 1) return;                      // attn wrote output directly

    const int tid  = threadIdx.x;
    const int w    = tid >> 6;
    const int lane = tid & 63;
    const int l16  = lane & 15;
    const int lg   = lane >> 4;

    const int perB = pfx(64, cl);
    const size_t base = (size_t)b * perB + pfx(qt, cl);

    float M[4] = {-INFINITY, -INFINITY, -INFINITY, -INFINITY};
    for (int s = 0; s < U; ++s)
        #pragma unroll
        for (int r = 0; r < 4; ++r)
            M[r] = fmaxf(M[r], partML[(base + s) * 128 + w * 16 + lg * 4 + r]);

    float L[4] = {0.f, 0.f, 0.f, 0.f};
    float acc[8];
    #pragma unroll
    for (int i = 0; i < 8; ++i) acc[i] = 0.f;

    for (int s = 0; s < U; ++s) {
        float e[4];
        #pragma unroll
        for (int r = 0; r < 4; ++r) {
            float ms = partML[(base + s) * 128 + w * 16 + lg * 4 + r];
            e[r] = exp2f(ms - M[r]);
            L[r] += partML[(base + s) * 128 + 64 + w * 16 + lg * 4 + r] * e[r];
        }
        short8 v = *(const short8*)(partO + (base + s) * 4096 + w * 1024 +
                                    lane * 16 + half * 8);
        #pragma unroll
        for (int j = 0; j < 8; ++j) {
            unsigned fb = ((unsigned)(unsigned short)v[j]) << 16;
            acc[j] += *(float*)&fb * e[j & 3];
        }
    }
    #pragma unroll
    for (int j = 0; j < 8; ++j) {
        int reg = half * 8 + j;
        int row = qt * 64 + w * 16 + lg * 4 + (j & 3);
        int dd  = (reg >> 2) * 16 + l16;
        out[((size_t)b * NN + row) * DD + dd] = acc[j] / L[j & 3];
    }
}

extern "C" void kernel_launch(void* const* d_in, const int* in_sizes, int n_in,
                              void* d_out, int out_size, void* d_ws, size_t ws_size,
                              hipStream_t stream) {
    const float* x  = (const float*)d_in[0];
    const float* Wq = (const float*)d_in[1];
    const float* Wk = (const float*)d_in[2];
    const float* Wv = (const float*)d_in[3];

    bf16* q  = (bf16*)d_ws;
    bf16* k  = q  + (size_t)BB * NN * DD;
    bf16* vT = k  + (size_t)BB * NN * DD;
    bf16* WT = vT + (size_t)BB * NN * DD;
    char* pbase = (char*)(WT + 3 * DD * DIN);
    size_t mis = (size_t)pbase & 15;
    if (mis) pbase += 16 - mis;
    size_t fixed = (size_t)(pbase - (char*)d_ws);

    int cl = 3, perB = 0;                    // 8 x 64-key tiles per unit
    for (; cl <= 4; ++cl) {
        perB = pfx(64, cl);
        size_t need = fixed + (size_t)BB * perB * (128 * 4 + 4096 * 2);
        if (need <= ws_size) break;
    }
    if (cl > 4) { cl = 4; perB = pfx(64, cl); }

    float* partML = (float*)pbase;
    unsigned short* partO = (unsigned short*)(partML + (size_t)BB * perB * 128);

    convw_kernel<<<(3 * DD * DIN) / 256, 256, 0, stream>>>(Wq, Wk, Wv, WT);
    proj_kernel<<<BB * NN / 64, 256, 0, stream>>>(x, WT, q, k, vT);
    attn_split_kernel<<<BB * perB, 256, 0, stream>>>(q, k, vT, partO, partML,
                                                     (float*)d_out, cl);
    combine_kernel<<<BB * 64 * 2, 256, 0, stream>>>(partO, partML, (float*)d_out, cl);
}

// Round 25
// 55.488 us; speedup vs baseline: 1.0851x; 1.0851x over previous
//
#include <hip/hip_runtime.h>
#include <hip/hip_bf16.h>

#define BB 4
#define NN 4096
#define DIN 512
#define DD 64

typedef __attribute__((ext_vector_type(8))) short short8;
typedef __attribute__((ext_vector_type(4))) float f32x4;
typedef __attribute__((ext_vector_type(4))) unsigned short us4;
typedef __attribute__((ext_vector_type(2))) unsigned int u32x2;
using bf16 = __hip_bfloat16;

// 0.125 * log2(e): QK^T scores come out in base-2 log-units
#define QSCALE 0.18033688011112042f

__device__ inline void mfma_16x16x32(f32x4& d, short8 a, short8 b) {
    asm("v_mfma_f32_16x16x32_bf16 %0, %1, %2, %0" : "+v"(d) : "v"(a), "v"(b));
}

__device__ inline unsigned cvt_pk_bf16(float lo, float hi) {
    unsigned r;
    asm("v_cvt_pk_bf16_f32 %0, %1, %2" : "=v"(r) : "v"(lo), "v"(hi));
    return r;
}

__device__ inline short8 load_cvt8(const float* __restrict__ src) {
    f32x4 f0 = *(const f32x4*)(src);
    f32x4 f1 = *(const f32x4*)(src + 4);
    bf16 t[8];
    #pragma unroll
    for (int j = 0; j < 4; ++j) t[j]     = __float2bfloat16(f0[j]);
    #pragma unroll
    for (int j = 0; j < 4; ++j) t[4 + j] = __float2bfloat16(f1[j]);
    return *(short8*)t;
}

// prefix of work units: U(qt) = ceil(T(qt)/2^cl), T = (qt+2)>>1  (64-row q-tiles)
__host__ __device__ inline int pfx(int qt, int cl) {
    int K = 2 << cl;                 // 2C
    int n = qt + K;
    int a = n >> (cl + 1);
    int r = n - (a << (cl + 1));
    return a * (a - 1) * (K >> 1) + r * a;
}

// ---------------- W transpose+convert: WT[g][kk] = W_{g/64}[kk][g%64] -----
__global__ __launch_bounds__(256) void convw_kernel(
    const float* __restrict__ Wq, const float* __restrict__ Wk,
    const float* __restrict__ Wv, bf16* __restrict__ WT)
{
    int idx = blockIdx.x * 256 + threadIdx.x;   // 3*64*512 = 98304
    int w   = idx >> 15;
    int rem = idx & 32767;
    int n   = rem >> 9;
    int kk  = rem & 511;
    const float* W = (w == 0) ? Wq : (w == 1) ? Wk : Wv;
    WT[idx] = __float2bfloat16(W[kk * DD + n]);
}

// ---------------- MFMA projection: 64 rows/block, LDS-staged x ------------
__global__ __launch_bounds__(256) void proj_kernel(
    const float* __restrict__ x, const bf16* __restrict__ WT,
    bf16* __restrict__ q, bf16* __restrict__ k, bf16* __restrict__ vT)
{
    __shared__ __align__(16) char xs[65536];   // 64 rows x 512 bf16, swizzled
    const int tid   = threadIdx.x;
    const int row0  = blockIdx.x * 64;
    const int b     = row0 >> 12;
    const int nrow0 = row0 & 4095;

    const float* xb = x + (size_t)row0 * DIN;
    #pragma unroll
    for (int i = 0; i < 16; ++i) {
        int c   = tid + i * 256;               // 0..4095
        int row = c >> 6;
        int cc  = c & 63;
        const float* src = xb + row * DIN + cc * 8;
        int off = row * 1024 + ((cc * 16) ^ ((row & 7) << 4));
        *(short8*)(xs + off) = load_cvt8(src);
    }
    __syncthreads();

    const int lane  = tid & 63;
    const int l16   = lane & 15;
    const int lg    = lane >> 4;
    const int wave  = tid >> 6;
    const int cbase = wave * 48;

    f32x4 acc[4][3];
    #pragma unroll
    for (int rt = 0; rt < 4; ++rt)
        #pragma unroll
        for (int ct = 0; ct < 3; ++ct) acc[rt][ct] = (f32x4){0.f, 0.f, 0.f, 0.f};

    const bf16* wb = WT + (size_t)(cbase + l16) * DIN + lg * 8;

    #pragma unroll 2
    for (int ks = 0; ks < 16; ++ks) {
        short8 a[4], bfr[3];
        #pragma unroll
        for (int rt = 0; rt < 4; ++rt) {
            int row = rt * 16 + l16;
            a[rt] = *(const short8*)(xs + row * 1024 +
                                     ((ks * 64 + lg * 16) ^ ((row & 7) << 4)));
        }
        #pragma unroll
        for (int ct = 0; ct < 3; ++ct)
            bfr[ct] = *(const short8*)(wb + ct * 16 * DIN + ks * 32);
        #pragma unroll
        for (int rt = 0; rt < 4; ++rt)
            #pragma unroll
            for (int ct = 0; ct < 3; ++ct)
                mfma_16x16x32(acc[rt][ct], a[rt], bfr[ct]);
    }

    #pragma unroll
    for (int ct = 0; ct < 3; ++ct) {
        int g = cbase + ct * 16 + l16;
        int w = g >> 6;
        int n = g & 63;
        #pragma unroll
        for (int rt = 0; rt < 4; ++rt) {
            if (w == 2) {
                us4 pv;
                #pragma unroll
                for (int r = 0; r < 4; ++r) {
                    bf16 hv = __float2bfloat16(acc[rt][ct][r]);
                    pv[r] = *(unsigned short*)&hv;
                }
                *(us4*)(vT + ((size_t)b * DD + n) * NN + nrow0 + rt * 16 + lg * 4) = pv;
            } else {
                bf16* dst = (w == 0) ? q : k;
                float sc  = (w == 0) ? QSCALE : 1.0f;
                #pragma unroll
                for (int r = 0; r < 4; ++r) {
                    int row = nrow0 + rt * 16 + lg * 4 + r;
                    dst[((size_t)b * NN + row) * DD + n] =
                        __float2bfloat16(acc[rt][ct][r] * sc);
                }
            }
        }
    }
}

// ---------------- equal-work split-KV flash attention ---------------------
// K/V tiles staged in LDS (XOR-swizzled), shared by the 4 waves of a block.
// swapped-QK layout: lane holds P[qrow = l16][keys ct*16 + lg*4 + r]
// swapped-PV layout: oacc[dt][r] = O[qrow = l16][dd = dt*16 + lg*4 + r]
// -> softmax stats are lane-local to O; no alpha shuffles.
__global__ __launch_bounds__(256) void attn_split_kernel(
    const bf16* __restrict__ q, const bf16* __restrict__ k,
    const bf16* __restrict__ vT,
    unsigned short* __restrict__ partO, float* __restrict__ partML,
    float* __restrict__ out, int cl)
{
    const int perB = pfx(64, cl);
    const int wblk = blockIdx.x;
    const int b    = wblk / perB;
    const int u    = wblk - b * perB;
    int lo = 0, hi = 63;
    while (lo < hi) {
        int mid = (lo + hi + 1) >> 1;
        if (pfx(mid, cl) <= u) lo = mid; else hi = mid - 1;
    }
    const int qt = lo;
    const int s  = u - pfx(qt, cl);
    const size_t sidx = (size_t)wblk;        // canonical partial slot

    const int T  = (qt + 2) >> 1;            // # 128-key tiles for this qt
    const int t0 = s << cl;
    int t1 = t0 + (1 << cl); if (t1 > T) t1 = T;
    const int K2 = 2 << cl;
    const int U  = (qt + K2) >> (cl + 1);    // # units for this qt

    const int wave = threadIdx.x >> 6;
    const int lane = threadIdx.x & 63;
    const int l16  = lane & 15;
    const int lg   = lane >> 4;

    __shared__ __align__(16) char klds[16384];      // 128 keys x 128B rows
    __shared__ __align__(16) char vlds[16384];      // 64 dd x 256B rows
    __shared__ __align__(16) char plds[4][4096];    // per-wave P buffer
    char* pbl = plds[wave];
    const int swz = (l16 & 7) << 4;

    const int row0g = qt * 64 + wave * 16;
    const int qrow  = row0g + l16;           // this lane's softmax row

    const bf16* qbase = q + ((size_t)b * NN + row0g + l16) * DD + lg * 8;
    short8 qfrag0 = *(const short8*)(qbase);
    short8 qfrag1 = *(const short8*)(qbase + 32);

    f32x4 oacc[4];
    #pragma unroll
    for (int dt = 0; dt < 4; ++dt) oacc[dt] = (f32x4){0.f, 0.f, 0.f, 0.f};
    float m = -INFINITY, l = 0.f;

    // ---- staging geometry: each wave stages 4KB of K and 4KB of V ----
    const char* kglob = (const char*)(k  + (size_t)b * NN * DD);  // +t*16384
    const char* vglob = (const char*)(vT + (size_t)b * DD * NN);  // +dd*8192 +t*256
    short8 kst[4], vst[4];
    int k_wr[4], v_wr[4], v_dd[4];
    #pragma unroll
    for (int i = 0; i < 4; ++i) {
        int L = wave * 4096 + i * 1024 + lane * 16;      // linear K offset
        k_wr[i] = L ^ (((L >> 7) & 7) << 4);
        int dd = wave * 16 + i * 4 + (lane >> 4);
        v_dd[i] = dd;
        v_wr[i] = dd * 256 + (((lane & 15) * 16) ^ ((dd & 7) << 4));
    }

    // prologue: load + write tile t0
    {
        const char* kt = kglob + (size_t)t0 * 16384;
        const char* vt = vglob + (size_t)t0 * 256;
        #pragma unroll
        for (int i = 0; i < 4; ++i)
            kst[i] = *(const short8*)(kt + wave * 4096 + i * 1024 + lane * 16);
        #pragma unroll
        for (int i = 0; i < 4; ++i)
            vst[i] = *(const short8*)(vt + (size_t)v_dd[i] * 8192 + (lane & 15) * 16);
        #pragma unroll
        for (int i = 0; i < 4; ++i) *(short8*)(klds + k_wr[i]) = kst[i];
        #pragma unroll
        for (int i = 0; i < 4; ++i) *(short8*)(vlds + v_wr[i]) = vst[i];
    }
    __syncthreads();

    #pragma unroll 1
    for (int t = t0; t < t1; ++t) {
        // ---- S = K Q^T from LDS (swapped operands) ----
        f32x4 sc[8];
        #pragma unroll
        for (int ct = 0; ct < 8; ++ct) sc[ct] = (f32x4){0.f, 0.f, 0.f, 0.f};
        __builtin_amdgcn_s_setprio(1);
        #pragma unroll
        for (int ct = 0; ct < 8; ++ct) {
            short8 kf0 = *(const short8*)(klds + (ct * 16 + l16) * 128 + ((lg * 16) ^ swz));
            short8 kf1 = *(const short8*)(klds + (ct * 16 + l16) * 128 + ((64 + lg * 16) ^ swz));
            mfma_16x16x32(sc[ct], kf0, qfrag0);
            mfma_16x16x32(sc[ct], kf1, qfrag1);
        }
        __builtin_amdgcn_s_setprio(0);

        // ---- prefetch next tile into registers (hidden under softmax+PV) ----
        if (t + 1 < t1) {
            const char* kt = kglob + (size_t)(t + 1) * 16384;
            const char* vt = vglob + (size_t)(t + 1) * 256;
            #pragma unroll
            for (int i = 0; i < 4; ++i)
                kst[i] = *(const short8*)(kt + wave * 4096 + i * 1024 + lane * 16);
            #pragma unroll
            for (int i = 0; i < 4; ++i)
                vst[i] = *(const short8*)(vt + (size_t)v_dd[i] * 8192 + (lane & 15) * 16);
        }

        // ---- causal mask (only on diagonal-touching tiles) ----
        if (t * 128 + 127 > row0g) {
            #pragma unroll
            for (int ct = 0; ct < 8; ++ct) {
                int gk = t * 128 + ct * 16 + lg * 4;
                #pragma unroll
                for (int r = 0; r < 4; ++r)
                    if (gk + r > qrow)
                        sc[ct][r] = -INFINITY;
            }
        }

        // ---- in-register softmax, base-2 (one q-row per lane) ----
        float m4[8];
        #pragma unroll
        for (int ct = 0; ct < 8; ++ct)
            m4[ct] = fmaxf(fmaxf(sc[ct][0], sc[ct][1]), fmaxf(sc[ct][2], sc[ct][3]));
        float mt = fmaxf(fmaxf(fmaxf(m4[0], m4[1]), fmaxf(m4[2], m4[3])),
                         fmaxf(fmaxf(m4[4], m4[5]), fmaxf(m4[6], m4[7])));
        mt = fmaxf(mt, __shfl_xor(mt, 16));
        mt = fmaxf(mt, __shfl_xor(mt, 32));

        float mn    = fmaxf(m, mt);
        float alpha = exp2f(m - mn);
        m = mn;

        float s4[8];
        #pragma unroll
        for (int ct = 0; ct < 8; ++ct) {
            float p0 = exp2f(sc[ct][0] - m);
            float p1 = exp2f(sc[ct][1] - m);
            float p2 = exp2f(sc[ct][2] - m);
            float p3 = exp2f(sc[ct][3] - m);
            sc[ct][0] = p0; sc[ct][1] = p1; sc[ct][2] = p2; sc[ct][3] = p3;
            s4[ct] = (p0 + p1) + (p2 + p3);
        }
        float ls = ((s4[0] + s4[1]) + (s4[2] + s4[3])) +
                   ((s4[4] + s4[5]) + (s4[6] + s4[7]));
        ls += __shfl_xor(ls, 16);
        ls += __shfl_xor(ls, 32);
        l = l * alpha + ls;

        // ---- O rescale: stats are lane-local in the transposed O layout ----
        #pragma unroll
        for (int dt = 0; dt < 4; ++dt)
            #pragma unroll
            for (int r = 0; r < 4; ++r)
                oacc[dt][r] *= alpha;

        // ---- P -> per-wave LDS (b64 writes, swizzled), read back B-frags ----
        #pragma unroll
        for (int ct = 0; ct < 8; ++ct) {
            u32x2 pw = (u32x2){cvt_pk_bf16(sc[ct][0], sc[ct][1]),
                               cvt_pk_bf16(sc[ct][2], sc[ct][3])};
            *(u32x2*)(pbl + l16 * 256 + ((ct * 32 + lg * 8) ^ swz)) = pw;
        }
        asm volatile("s_waitcnt lgkmcnt(0)" ::: "memory");
        short8 pa[4];
        #pragma unroll
        for (int kc = 0; kc < 4; ++kc)
            pa[kc] = *(const short8*)(pbl + l16 * 256 + ((kc * 64 + lg * 16) ^ swz));

        // ---- O^T += V^T P^T : A = V fragment, B = P fragment (swapped) ----
        __builtin_amdgcn_s_setprio(1);
        #pragma unroll
        for (int dt = 0; dt < 4; ++dt) {
            #pragma unroll
            for (int kc = 0; kc < 4; ++kc) {
                short8 vf = *(const short8*)(vlds + (dt * 16 + l16) * 256 +
                                             ((kc * 64 + lg * 16) ^ swz));
                mfma_16x16x32(oacc[dt], vf, pa[kc]);
            }
        }
        __builtin_amdgcn_s_setprio(0);

        // ---- publish next staged tile ----
        if (t + 1 < t1) {
            __syncthreads();                 // all waves done reading tile t
            #pragma unroll
            for (int i = 0; i < 4; ++i) *(short8*)(klds + k_wr[i]) = kst[i];
            #pragma unroll
            for (int i = 0; i < 4; ++i) *(short8*)(vlds + v_wr[i]) = vst[i];
            __syncthreads();                 // staged tile ready
        }
    }

    if (U == 1) {
        // sole unit for this (b,qt): write normalized output directly
        float inv = 1.f / l;
        float* ob = out + ((size_t)b * NN + row0g + l16) * DD;
        #pragma unroll
        for (int dt = 0; dt < 4; ++dt) {
            f32x4 v = oacc[dt] * inv;
            *(f32x4*)(ob + dt * 16 + lg * 4) = v;
        }
        return;
    }

    // ---- write partials: bf16, [sidx][wave][lane][16 regs] (contiguous) ----
    // reg dt*4+r = O[qrow = wave*16 + l16][dd = dt*16 + lg*4 + r]
    {
        unsigned short hv[16];
        #pragma unroll
        for (int dt = 0; dt < 4; ++dt)
            #pragma unroll
            for (int r = 0; r < 4; ++r) {
                bf16 h = __float2bfloat16(oacc[dt][r]);
                hv[dt * 4 + r] = *(unsigned short*)&h;
            }
        unsigned short* dst = partO + sidx * 4096 + wave * 1024 + lane * 16;
        *(short8*)(dst)     = *(short8*)(hv);
        *(short8*)(dst + 8) = *(short8*)(hv + 8);
    }
    if (lg == 0) {
        partML[sidx * 128 + wave * 16 + l16]      = m;
        partML[sidx * 128 + 64 + wave * 16 + l16] = l;
    }
}

// ---------------- combine partials: 512 blocks, 8 regs each ---------------
// all 16 regs of a lane belong to ONE q-row -> scalar stats
__global__ __launch_bounds__(256) void combine_kernel(
    const unsigned short* __restrict__ partO, const float* __restrict__ partML,
    float* __restrict__ out, int cl)
{
    const int blk2 = blockIdx.x;             // (b*64+qt)*2 + half
    const int half = blk2 & 1;
    const int blk  = blk2 >> 1;
    const int qt   = blk & 63;
    const int b    = blk >> 6;

    const int K2 = 2 << cl;
    const int U  = (qt + K2) >> (cl + 1);    // # work units for this qt
    if (U == 1) return;                      // attn wrote output directly

    const int tid  = threadIdx.x;
    const int w    = tid >> 6;
    const int lane = tid & 63;
    const int l16  = lane & 15;
    const int lg   = lane >> 4;

    const int perB = pfx(64, cl);
    const size_t base = (size_t)b * perB + pfx(qt, cl);

    float M = -INFINITY;
    for (int s = 0; s < U; ++s)
        M = fmaxf(M, partML[(base + s) * 128 + w * 16 + l16]);

    float L = 0.f;
    float acc[8];
    #pragma unroll
    for (int i = 0; i < 8; ++i) acc[i] = 0.f;

    for (int s = 0; s < U; ++s) {
        float ms = partML[(base + s) * 128 + w * 16 + l16];
        float e  = exp2f(ms - M);
        L += partML[(base + s) * 128 + 64 + w * 16 + l16] * e;
        short8 v = *(const short8*)(partO + (base + s) * 4096 + w * 1024 +
                                    lane * 16 + half * 8);
        #pragma unroll
        for (int j = 0; j < 8; ++j) {
            unsigned fb = ((unsigned)(unsigned short)v[j]) << 16;
            acc[j] += *(float*)&fb * e;
        }
    }
    float inv = 1.f / L;
    const int row = qt * 64 + w * 16 + l16;
    float* ob = out + ((size_t)b * NN + row) * DD;
    // regs half*8+j -> dt = (half*8+j)>>2, r = j&3 ; dd = dt*16 + lg*4 + r
    f32x4 o0 = (f32x4){acc[0], acc[1], acc[2], acc[3]} * inv;
    f32x4 o1 = (f32x4){acc[4], acc[5], acc[6], acc[7]} * inv;
    *(f32x4*)(ob + (half * 2 + 0) * 16 + lg * 4) = o0;
    *(f32x4*)(ob + (half * 2 + 1) * 16 + lg * 4) = o1;
}

extern "C" void kernel_launch(void* const* d_in, const int* in_sizes, int n_in,
                              void* d_out, int out_size, void* d_ws, size_t ws_size,
                              hipStream_t stream) {
    const float* x  = (const float*)d_in[0];
    const float* Wq = (const float*)d_in[1];
    const float* Wk = (const float*)d_in[2];
    const float* Wv = (const float*)d_in[3];

    bf16* q  = (bf16*)d_ws;
    bf16* k  = q  + (size_t)BB * NN * DD;
    bf16* vT = k  + (size_t)BB * NN * DD;
    bf16* WT = vT + (size_t)BB * NN * DD;
    char* pbase = (char*)(WT + 3 * DD * DIN);
    size_t mis = (size_t)pbase & 15;
    if (mis) pbase += 16 - mis;
    size_t fixed = (size_t)(pbase - (char*)d_ws);

    int cl = 2, perB = 0;                    // 4-tile work units (best known)
    for (; cl <= 3; ++cl) {
        perB = pfx(64, cl);
        size_t need = fixed + (size_t)BB * perB * (128 * 4 + 4096 * 2);
        if (need <= ws_size) break;
    }
    if (cl > 3) { cl = 3; perB = pfx(64, cl); }

    float* partML = (float*)pbase;
    unsigned short* partO = (unsigned short*)(partML + (size_t)BB * perB * 128);

    convw_kernel<<<(3 * DD * DIN) / 256, 256, 0, stream>>>(Wq, Wk, Wv, WT);
    proj_kernel<<<BB * NN / 64, 256, 0, stream>>>(x, WT, q, k, vT);
    attn_split_kernel<<<BB * perB, 256, 0, stream>>>(q, k, vT, partO, partML,
                                                     (float*)d_out, cl);
    combine_kernel<<<BB * 64 * 2, 256, 0, stream>>>(partO, partML, (float*)d_out, cl);
}